// Round 1
// baseline (89.505 us; speedup 1.0000x reference)
//
#include <hip/hip_runtime.h>
#include <math.h>

#define NS 256
#define EMB 120
#define NBLK 60
#define MODES 16
#define NPH 8

__device__ __forceinline__ float2 cmul(float2 a, float2 b) {
    float2 r;
    r.x = fmaf(a.x, b.x, -(a.y * b.y));
    r.y = fmaf(a.x, b.y,   a.y * b.x);
    return r;
}

// Kernel A: x_emb = sigmoid(x@W.T+b); build V = U[:, :, 0:8] per sample.
// Columns of U evolve independently under left-multiplication by the 2x2 blocks,
// so we only track the 16x8 slice (8 column-threads, 16 complex rows each).
__global__ __launch_bounds__(128) void emb_v_kernel(
    const float* __restrict__ x, const float* __restrict__ W,
    const float* __restrict__ bias, float* __restrict__ out_emb,
    float2* __restrict__ Vws)
{
    const int s = blockIdx.x;
    const int t = threadIdx.x;
    __shared__ float emb[EMB];
    __shared__ float ctA[NBLK], stA[NBLK], exA[NBLK], eyA[NBLK];

    if (t < EMB) {
        const float* xr = x + s * 64;
        const float* wr = W + t * 64;
        float acc = bias[t];
        #pragma unroll
        for (int k = 0; k < 64; ++k) acc = fmaf(xr[k], wr[k], acc);
        float e = 1.0f / (1.0f + expf(-acc));
        emb[t] = e;
        out_emb[s * EMB + t] = e;
    }
    __syncthreads();

    if (t < NBLK) {
        float th = emb[2 * t]     * 1.57079632679489662f;  // pi/2
        float ph = emb[2 * t + 1] * 6.28318530717958648f;  // 2*pi
        float st, ct, sp, cp;
        sincosf(th, &st, &ct);
        sincosf(ph, &sp, &cp);
        ctA[t] = ct; stA[t] = st; exA[t] = cp; eyA[t] = sp;
    }
    __syncthreads();

    if (t < NPH) {
        const int c = t;  // column 0..7
        float2 u[MODES];
        #pragma unroll
        for (int m = 0; m < MODES; ++m) {
            u[m].x = (m == c) ? 1.0f : 0.0f;
            u[m].y = 0.0f;
        }
        int bi = 0;
        #pragma unroll
        for (int d = 0; d < 8; ++d) {
            const int off = d & 1;
            const int nb = 8 - off;
            #pragma unroll
            for (int k = 0; k < nb; ++k) {
                float ct = ctA[bi], st = stA[bi], ex = exA[bi], ey = eyA[bi];
                ++bi;
                const int r0 = off + 2 * k;
                float2 u0 = u[r0], u1 = u[r0 + 1];
                float2 n0, n1;
                // row0 = ep*ct*u0 - st*u1 ; row1 = ep*st*u0 + ct*u1
                n0.x = ex * ct * u0.x - ey * ct * u0.y - st * u1.x;
                n0.y = ex * ct * u0.y + ey * ct * u0.x - st * u1.y;
                n1.x = ex * st * u0.x - ey * st * u0.y + ct * u1.x;
                n1.y = ex * st * u0.y + ey * st * u0.x + ct * u1.y;
                u[r0] = n0; u[r0 + 1] = n1;
            }
        }
        #pragma unroll
        for (int m = 0; m < MODES; ++m)
            Vws[(s * MODES + m) * NPH + c] = u[m];
    }
}

// Kernel B: per (a,b) pair: G = V[a]^H V[b] (8x8 complex), perm via Gray-code
// Ryser, K[a,b] = |perm|^2 (diag forced to 1). Block = 16x16 pair tile.
__global__ __launch_bounds__(256) void perm_kernel(
    const float2* __restrict__ Vws, float* __restrict__ outK)
{
    __shared__ float2 lds_a[16][130];   // +2 pad: row stride 260 dwords -> banks 4 apart
    __shared__ float2 lds_b[16][130];

    const int tid = threadIdx.x;
    const int ta = blockIdx.x >> 4;
    const int tb = blockIdx.x & 15;

    // Stage V tiles: 16 samples x 128 float2 each side, float4 loads.
    const float4* srcA = (const float4*)(Vws + (size_t)ta * 16 * 128);
    const float4* srcB = (const float4*)(Vws + (size_t)tb * 16 * 128);
    #pragma unroll
    for (int q = 0; q < 4; ++q) {
        int idx = q * 256 + tid;        // 0..1023 float4s = 16 rows x 64
        int row = idx >> 6;
        int pos = (idx & 63) * 2;
        float4 fa = srcA[idx];
        float4 fb = srcB[idx];
        lds_a[row][pos].x     = fa.x; lds_a[row][pos].y     = fa.y;
        lds_a[row][pos + 1].x = fa.z; lds_a[row][pos + 1].y = fa.w;
        lds_b[row][pos].x     = fb.x; lds_b[row][pos].y     = fb.y;
        lds_b[row][pos + 1].x = fb.z; lds_b[row][pos + 1].y = fb.w;
    }
    __syncthreads();

    const int tx = tid & 15;   // b within tile
    const int ty = tid >> 4;   // a within tile

    float2 G[8][8];
    #pragma unroll
    for (int i = 0; i < 8; ++i)
        #pragma unroll
        for (int j = 0; j < 8; ++j) { G[i][j].x = 0.f; G[i][j].y = 0.f; }

    // G[i][j] = sum_m conj(Va[m][i]) * Vb[m][j]
    #pragma unroll 1
    for (int m = 0; m < 16; ++m) {
        float2 va[8], vb[8];
        #pragma unroll
        for (int i = 0; i < 8; ++i) va[i] = lds_a[ty][m * 8 + i];
        #pragma unroll
        for (int j = 0; j < 8; ++j) vb[j] = lds_b[tx][m * 8 + j];
        #pragma unroll
        for (int i = 0; i < 8; ++i)
            #pragma unroll
            for (int j = 0; j < 8; ++j) {
                G[i][j].x = fmaf(va[i].x, vb[j].x, fmaf(va[i].y, vb[j].y, G[i][j].x));
                G[i][j].y = fmaf(va[i].x, vb[j].y, fmaf(-va[i].y, vb[j].x, G[i][j].y));
            }
    }

    // Gray-code Ryser. t = 16*o + u. Column toggled at step t: j = ctz(t).
    // add iff bit (j+1) of t == 0. Term sign: -1 if t odd, +1 if t even.
    float2 rs[8];
    #pragma unroll
    for (int i = 0; i < 8; ++i) { rs[i].x = 0.f; rs[i].y = 0.f; }
    float2 acc; acc.x = 0.f; acc.y = 0.f;

#define RSTEP(J, S, TS) do {                                          \
        _Pragma("unroll")                                             \
        for (int i = 0; i < 8; ++i) {                                 \
            rs[i].x = fmaf((S), G[i][J].x, rs[i].x);                  \
            rs[i].y = fmaf((S), G[i][J].y, rs[i].y);                  \
        }                                                             \
        float2 p01 = cmul(rs[0], rs[1]);                              \
        float2 p23 = cmul(rs[2], rs[3]);                              \
        float2 p45 = cmul(rs[4], rs[5]);                              \
        float2 p67 = cmul(rs[6], rs[7]);                              \
        float2 q0  = cmul(p01, p23);                                  \
        float2 q1  = cmul(p45, p67);                                  \
        float2 pr  = cmul(q0, q1);                                    \
        acc.x = fmaf((TS), pr.x, acc.x);                              \
        acc.y = fmaf((TS), pr.y, acc.y);                              \
    } while (0)

    #pragma unroll 1
    for (int o = 0; o < 16; ++o) {
        const float s8 = (o & 1) ? -1.f : 1.f;   // u=8: add iff bit4(t)=o&1 == 0
        RSTEP(0,  1.f, -1.f);   // u=1
        RSTEP(1,  1.f,  1.f);   // u=2
        RSTEP(0, -1.f, -1.f);   // u=3
        RSTEP(2,  1.f,  1.f);   // u=4
        RSTEP(0,  1.f, -1.f);   // u=5
        RSTEP(1, -1.f,  1.f);   // u=6
        RSTEP(0, -1.f, -1.f);   // u=7
        RSTEP(3,  s8,   1.f);   // u=8
        RSTEP(0,  1.f, -1.f);   // u=9
        RSTEP(1,  1.f,  1.f);   // u=10
        RSTEP(0, -1.f, -1.f);   // u=11
        RSTEP(2, -1.f,  1.f);   // u=12
        RSTEP(0,  1.f, -1.f);   // u=13
        RSTEP(1, -1.f,  1.f);   // u=14
        RSTEP(0, -1.f, -1.f);   // u=15
        if (o < 15) {           // u=16: t = 16*(o+1), column 4+ctz(o+1)
            const int p = o + 1;
            const int jj = __builtin_ctz(p);                   // 0..3
            const float s16 = ((p >> (jj + 1)) & 1) ? -1.f : 1.f;
            float2 col[8];
            #pragma unroll
            for (int i = 0; i < 8; ++i) {
                float2 s01 = (jj & 1) ? G[i][5] : G[i][4];
                float2 s23 = (jj & 1) ? G[i][7] : G[i][6];
                col[i] = (jj & 2) ? s23 : s01;
            }
            #pragma unroll
            for (int i = 0; i < 8; ++i) {
                rs[i].x = fmaf(s16, col[i].x, rs[i].x);
                rs[i].y = fmaf(s16, col[i].y, rs[i].y);
            }
            float2 p01 = cmul(rs[0], rs[1]);
            float2 p23 = cmul(rs[2], rs[3]);
            float2 p45 = cmul(rs[4], rs[5]);
            float2 p67 = cmul(rs[6], rs[7]);
            float2 q0  = cmul(p01, p23);
            float2 q1  = cmul(p45, p67);
            float2 pr  = cmul(q0, q1);
            acc.x += pr.x;   // t even -> sign +1
            acc.y += pr.y;
        }
    }
#undef RSTEP

    const int a = ta * 16 + ty;
    const int b = tb * 16 + tx;
    float K = fmaf(acc.x, acc.x, acc.y * acc.y);
    if (a == b) K = 1.0f;
    outK[a * 256 + b] = K;
}

extern "C" void kernel_launch(void* const* d_in, const int* in_sizes, int n_in,
                              void* d_out, int out_size, void* d_ws, size_t ws_size,
                              hipStream_t stream) {
    const float* x    = (const float*)d_in[0];   // 256*64
    const float* W    = (const float*)d_in[1];   // 120*64
    const float* bias = (const float*)d_in[2];   // 120
    float* out     = (float*)d_out;
    float* out_emb = out;              // 256*120
    float* outK    = out + NS * EMB;   // 256*256
    float2* Vws    = (float2*)d_ws;    // 256*16*8 float2 = 256 KB

    emb_v_kernel<<<NS, 128, 0, stream>>>(x, W, bias, out_emb, Vws);
    perm_kernel<<<NS, 256, 0, stream>>>(Vws, outK);
}

// Round 2
// 80.887 us; speedup vs baseline: 1.1065x; 1.1065x over previous
//
#include <hip/hip_runtime.h>
#include <math.h>

#define NS 256
#define EMB 120
#define NBLK 60
#define MODES 16
#define NPH 8

__device__ __forceinline__ float2 cmul(float2 a, float2 b) {
    float2 r;
    r.x = fmaf(a.x, b.x, -(a.y * b.y));
    r.y = fmaf(a.x, b.y,   a.y * b.x);
    return r;
}

// Kernel A: x_emb = sigmoid(x@W.T+b); build V = U[:, :, 0:8] per sample.
__global__ __launch_bounds__(128) void emb_v_kernel(
    const float* __restrict__ x, const float* __restrict__ W,
    const float* __restrict__ bias, float* __restrict__ out_emb,
    float2* __restrict__ Vws)
{
    const int s = blockIdx.x;
    const int t = threadIdx.x;
    __shared__ float emb[EMB];
    __shared__ float ctA[NBLK], stA[NBLK], exA[NBLK], eyA[NBLK];

    if (t < EMB) {
        const float* xr = x + s * 64;
        const float* wr = W + t * 64;
        float acc = bias[t];
        #pragma unroll
        for (int k = 0; k < 64; ++k) acc = fmaf(xr[k], wr[k], acc);
        float e = 1.0f / (1.0f + expf(-acc));
        emb[t] = e;
        out_emb[s * EMB + t] = e;
    }
    __syncthreads();

    if (t < NBLK) {
        float th = emb[2 * t]     * 1.57079632679489662f;  // pi/2
        float ph = emb[2 * t + 1] * 6.28318530717958648f;  // 2*pi
        float st, ct, sp, cp;
        sincosf(th, &st, &ct);
        sincosf(ph, &sp, &cp);
        ctA[t] = ct; stA[t] = st; exA[t] = cp; eyA[t] = sp;
    }
    __syncthreads();

    if (t < NPH) {
        const int c = t;  // column 0..7
        float2 u[MODES];
        #pragma unroll
        for (int m = 0; m < MODES; ++m) {
            u[m].x = (m == c) ? 1.0f : 0.0f;
            u[m].y = 0.0f;
        }
        int bi = 0;
        #pragma unroll
        for (int d = 0; d < 8; ++d) {
            const int off = d & 1;
            const int nb = 8 - off;
            #pragma unroll
            for (int k = 0; k < nb; ++k) {
                float ct = ctA[bi], st = stA[bi], ex = exA[bi], ey = eyA[bi];
                ++bi;
                const int r0 = off + 2 * k;
                float2 u0 = u[r0], u1 = u[r0 + 1];
                float2 n0, n1;
                n0.x = ex * ct * u0.x - ey * ct * u0.y - st * u1.x;
                n0.y = ex * ct * u0.y + ey * ct * u0.x - st * u1.y;
                n1.x = ex * st * u0.x - ey * st * u0.y + ct * u1.x;
                n1.y = ex * st * u0.y + ey * st * u0.x + ct * u1.y;
                u[r0] = n0; u[r0 + 1] = n1;
            }
        }
        #pragma unroll
        for (int m = 0; m < MODES; ++m)
            Vws[(s * MODES + m) * NPH + c] = u[m];
    }
}

// Kernel B: per (a,b) pair: G = V[a]^H V[b] (8x8 complex), perm via Gray-code
// GLYNN formula (128 terms, half of Ryser-255):
//   perm = 2^-7 * sum_{delta in {+-1}^8, d0=+1} (prod delta) prod_i sum_j d_j G[i][j]
// Gray order over the 7 free bits: inner 7 steps toggle cols 1,2,3 with
// compile-time +-2 coefficients; every 8th step toggles col 4+ctz(q) (uniform).
// __launch_bounds__(256,1): allow full VGPR budget so G[8][8] never spills.
__global__ __launch_bounds__(256, 1) void perm_kernel(
    const float2* __restrict__ Vws, float* __restrict__ outK)
{
    __shared__ float2 lds_a[16][130];   // +2 pad: rows land on distinct banks
    __shared__ float2 lds_b[16][130];

    const int tid = threadIdx.x;
    const int ta = blockIdx.x >> 4;
    const int tb = blockIdx.x & 15;

    const float4* srcA = (const float4*)(Vws + (size_t)ta * 16 * 128);
    const float4* srcB = (const float4*)(Vws + (size_t)tb * 16 * 128);
    #pragma unroll
    for (int q = 0; q < 4; ++q) {
        int idx = q * 256 + tid;        // 0..1023 float4s = 16 rows x 64
        int row = idx >> 6;
        int pos = (idx & 63) * 2;
        float4 fa = srcA[idx];
        float4 fb = srcB[idx];
        lds_a[row][pos].x     = fa.x; lds_a[row][pos].y     = fa.y;
        lds_a[row][pos + 1].x = fa.z; lds_a[row][pos + 1].y = fa.w;
        lds_b[row][pos].x     = fb.x; lds_b[row][pos].y     = fb.y;
        lds_b[row][pos + 1].x = fb.z; lds_b[row][pos + 1].y = fb.w;
    }
    __syncthreads();

    const int tx = tid & 15;   // b within tile
    const int ty = tid >> 4;   // a within tile

    float2 G[8][8];
    #pragma unroll
    for (int i = 0; i < 8; ++i)
        #pragma unroll
        for (int j = 0; j < 8; ++j) { G[i][j].x = 0.f; G[i][j].y = 0.f; }

    // G[i][j] = sum_m conj(Va[m][i]) * Vb[m][j]
    #pragma unroll 1
    for (int m = 0; m < 16; ++m) {
        float2 va[8], vb[8];
        #pragma unroll
        for (int i = 0; i < 8; ++i) va[i] = lds_a[ty][m * 8 + i];
        #pragma unroll
        for (int j = 0; j < 8; ++j) vb[j] = lds_b[tx][m * 8 + j];
        #pragma unroll
        for (int i = 0; i < 8; ++i)
            #pragma unroll
            for (int j = 0; j < 8; ++j) {
                G[i][j].x = fmaf(va[i].x, vb[j].x, fmaf(va[i].y, vb[j].y, G[i][j].x));
                G[i][j].y = fmaf(va[i].x, vb[j].y, fmaf(-va[i].y, vb[j].x, G[i][j].y));
            }
    }

    // rs init: all delta = +1
    float2 rs[8];
    #pragma unroll
    for (int i = 0; i < 8; ++i) {
        float sx = 0.f, sy = 0.f;
        #pragma unroll
        for (int j = 0; j < 8; ++j) { sx += G[i][j].x; sy += G[i][j].y; }
        rs[i].x = sx; rs[i].y = sy;
    }

    float2 acc;

#define PRODTREE(OUT) do {                                            \
        float2 p01 = cmul(rs[0], rs[1]);                              \
        float2 p23 = cmul(rs[2], rs[3]);                              \
        float2 p45 = cmul(rs[4], rs[5]);                              \
        float2 p67 = cmul(rs[6], rs[7]);                              \
        float2 q0  = cmul(p01, p23);                                  \
        float2 q1  = cmul(p45, p67);                                  \
        OUT = cmul(q0, q1);                                           \
    } while (0)

#define UPD(J, S) do {                                                \
        _Pragma("unroll")                                             \
        for (int i = 0; i < 8; ++i) {                                 \
            rs[i].x = fmaf((S), G[i][J].x, rs[i].x);                  \
            rs[i].y = fmaf((S), G[i][J].y, rs[i].y);                  \
        }                                                             \
    } while (0)

#define TERM(TS) do {                                                 \
        float2 pr; PRODTREE(pr);                                      \
        acc.x = fmaf((TS), pr.x, acc.x);                              \
        acc.y = fmaf((TS), pr.y, acc.y);                              \
    } while (0)

    PRODTREE(acc);   // t=0 term, sign +

    #pragma unroll 1
    for (int p = 0; p < 16; ++p) {
        const float s4 = (p & 1) ? 2.f : -2.f;
        UPD(1, -2.f); TERM(-1.f);   // u=1
        UPD(2, -2.f); TERM( 1.f);   // u=2
        UPD(1,  2.f); TERM(-1.f);   // u=3
        UPD(3,  s4 ); TERM( 1.f);   // u=4
        UPD(1, -2.f); TERM(-1.f);   // u=5
        UPD(2,  2.f); TERM( 1.f);   // u=6
        UPD(1,  2.f); TERM(-1.f);   // u=7
        if (p < 15) {               // u=8: t=8q, toggles column 4+ctz(q)
            const int q = p + 1;
            const int c = __builtin_ctz(q);                 // 0..3
            const float s = ((q >> (c + 1)) & 1) ? 2.f : -2.f;
            switch (c) {            // uniform scalar branch, no cndmask cascade
                case 0: UPD(4, s); break;
                case 1: UPD(5, s); break;
                case 2: UPD(6, s); break;
                default: UPD(7, s); break;
            }
            TERM(1.f);
        }
    }
#undef UPD
#undef TERM
#undef PRODTREE

    const int a = ta * 16 + ty;
    const int b = tb * 16 + tx;
    // perm = acc / 128  ->  |perm|^2 = |acc|^2 / 16384
    float K = fmaf(acc.x, acc.x, acc.y * acc.y) * (1.0f / 16384.0f);
    if (a == b) K = 1.0f;
    outK[a * 256 + b] = K;
}

extern "C" void kernel_launch(void* const* d_in, const int* in_sizes, int n_in,
                              void* d_out, int out_size, void* d_ws, size_t ws_size,
                              hipStream_t stream) {
    const float* x    = (const float*)d_in[0];   // 256*64
    const float* W    = (const float*)d_in[1];   // 120*64
    const float* bias = (const float*)d_in[2];   // 120
    float* out     = (float*)d_out;
    float* out_emb = out;              // 256*120
    float* outK    = out + NS * EMB;   // 256*256
    float2* Vws    = (float2*)d_ws;    // 256*16*8 float2 = 32 KB

    emb_v_kernel<<<NS, 128, 0, stream>>>(x, W, bias, out_emb, Vws);
    perm_kernel<<<NS, 256, 0, stream>>>(Vws, outK);
}